// Round 1
// baseline (335.186 us; speedup 1.0000x reference)
//
#include <hip/hip_runtime.h>
#include <math.h>

// Problem constants: B=4, N=2048, D=1024, H=16, DH=64
constexpr int Bc  = 4;
constexpr int Nc  = 2048;
constexpr int Dc  = 1024;
constexpr int Hc  = 16;
constexpr int DHc = 64;
constexpr int Mrows = Bc * Nc;  // 8192

typedef unsigned short ushortT;
typedef __attribute__((ext_vector_type(8))) short bf16x8;
typedef __attribute__((ext_vector_type(2))) unsigned short u16x2;
typedef __attribute__((ext_vector_type(4))) unsigned short u16x4;
typedef __attribute__((ext_vector_type(4))) float f32x4;

// 1/sqrt(DH) * log2(e): folded into Q so softmax is exp2(s) directly.
#define QSCALE 0.18033688011112043f

// async global->LDS, 16B per lane; LDS dest must be wave-uniform base + lane*16
#define GLD_LDS16(g, l)                                                        \
  __builtin_amdgcn_global_load_lds(                                            \
      (const __attribute__((address_space(1))) void*)(g),                      \
      (__attribute__((address_space(3))) void*)(l), 16, 0, 0)

__device__ inline ushortT f2bf(float f) {
  unsigned int u = __float_as_uint(f);
  u += 0x7fffu + ((u >> 16) & 1u);  // round-to-nearest-even
  return (ushortT)(u >> 16);
}

// fast 2^x on the transcendental pipe (v_exp_f32)
__device__ inline float fexp2(float x) { return __builtin_amdgcn_exp2f(x); }

// ---------------------------------------------------------------------------
// fp32 -> bf16 conversion of x and the 4 weight matrices (unchanged, verified)
// ---------------------------------------------------------------------------
__global__ __launch_bounds__(256) void cvt_kernel(
    const float* __restrict__ x, const float* __restrict__ wq,
    const float* __restrict__ wk, const float* __restrict__ wv,
    const float* __restrict__ wo, ushortT* __restrict__ dst) {
  const int g = blockIdx.x * 256 + threadIdx.x;  // float4 index
  const float* src;
  size_t soff, doff;
  if (g < 2097152) {
    src = x;
    soff = (size_t)g * 4;
    doff = soff;
  } else {
    const int t = g - 2097152;
    const int w = t >> 18;
    const int off = t & 262143;
    src = (w == 0) ? wq : (w == 1) ? wk : (w == 2) ? wv : wo;
    soff = (size_t)off * 4;
    doff = 8388608u + (size_t)w * 1048576u + (size_t)off * 4;
  }
  float4 v = *(const float4*)(src + soff);
  ushort4 o = make_ushort4(f2bf(v.x), f2bf(v.y), f2bf(v.z), f2bf(v.w));
  *(ushort4*)(dst + doff) = o;
}

// ---------------------------------------------------------------------------
// MFMA GEMM C = A @ W^T.  BK=64 via two m97-layout 32-k panels: 32 MFMA per
// barrier pair (halves barrier-drain count vs BK=32). LDS 32 KB.
// QKV=1: wsel=bx>>3 selects Wq/Wk/Wv; Q output (wsel==0) pre-scaled by QSCALE.
// (unchanged this round)
// ---------------------------------------------------------------------------
template <int QKV>
__global__ __launch_bounds__(256) void mfma_gemm(const ushortT* __restrict__ A,
                                                 const ushortT* __restrict__ W0,
                                                 void* __restrict__ C0) {
  __shared__ ushortT As[2][128 * 32];  // [panel][row][32]
  __shared__ ushortT Bs[2][128 * 32];

  const int tid = threadIdx.x;
  const int wave = tid >> 6, lane = tid & 63;
  const int quad = lane >> 4, lrow = lane & 15;
  const int bx = blockIdx.x, by = blockIdx.y;
  const int wsel = QKV ? (bx >> 3) : 0;
  const int e0 = QKV ? ((bx & 7) * 128) : (bx * 128);
  const int m0 = by * 128;
  const ushortT* Wp = W0 + (size_t)wsel * (Dc * Dc);
  const float oscale = (QKV && wsel == 0) ? QSCALE : 1.0f;

  const ushortT* ag = A  + (size_t)(m0 + wave * 32 + (lane >> 2)) * Dc + (lane & 3) * 8;
  const ushortT* bg = Wp + (size_t)(e0 + wave * 32 + (lane >> 2)) * Dc + (lane & 3) * 8;
  const int lbase = wave * 1024 + lane * 8;

  f32x4 acc[4][4];
#pragma unroll
  for (int i = 0; i < 4; ++i)
#pragma unroll
    for (int j = 0; j < 4; ++j) acc[i][j] = (f32x4){0.f, 0.f, 0.f, 0.f};

  const int wm = (wave >> 1) * 64, wn = (wave & 1) * 64;

  for (int k0 = 0; k0 < Dc; k0 += 64) {
    __syncthreads();
#pragma unroll
    for (int p = 0; p < 2; ++p) {
      GLD_LDS16(ag + p * 32, &As[p][lbase]);
      GLD_LDS16(ag + p * 32 + 16 * Dc, &As[p][lbase + 512]);
      GLD_LDS16(bg + p * 32, &Bs[p][lbase]);
      GLD_LDS16(bg + p * 32 + 16 * Dc, &Bs[p][lbase + 512]);
    }
    ag += 64;
    bg += 64;
    __syncthreads();

#pragma unroll
    for (int p = 0; p < 2; ++p) {
      bf16x8 af[4], bf[4];
#pragma unroll
      for (int mt = 0; mt < 4; ++mt)
        af[mt] = *(const bf16x8*)(&As[p][(wm + mt * 16 + lrow) * 32 + quad * 8]);
#pragma unroll
      for (int nt = 0; nt < 4; ++nt)
        bf[nt] = *(const bf16x8*)(&Bs[p][(wn + nt * 16 + lrow) * 32 + quad * 8]);
#pragma unroll
      for (int mt = 0; mt < 4; ++mt)
#pragma unroll
        for (int nt = 0; nt < 4; ++nt)
          acc[mt][nt] = __builtin_amdgcn_mfma_f32_16x16x32_bf16(
              af[mt], bf[nt], acc[mt][nt], 0, 0, 0);
    }
  }

#pragma unroll
  for (int mt = 0; mt < 4; ++mt) {
#pragma unroll
    for (int nt = 0; nt < 4; ++nt) {
#pragma unroll
      for (int r = 0; r < 4; ++r) {
        const int m = m0 + wm + mt * 16 + quad * 4 + r;
        const int e = e0 + wn + nt * 16 + lrow;
        const float v = acc[mt][nt][r] * oscale;
        if (QKV) {
          const int b = m >> 11, n = m & 2047;
          const int h = e >> 6, dh = e & 63;
          ushortT* C = (ushortT*)C0 + (size_t)wsel * ((size_t)Mrows * Dc);
          C[(((size_t)(b * Hc + h)) * Nc + n) * DHc + dh] = f2bf(v);
        } else {
          ((float*)C0)[(size_t)m * Dc + e] = v;
        }
      }
    }
  }
}

// ---------------------------------------------------------------------------
// MFMA flash attention, fixed-m softmax. BQ=256.
// Round-6 restructure (latency-bound fix per rocprof: Occ 18.6%, Mfma 26%,
// VALU 33%, 6.36M LDS bank-conflict cycles):
//   * 512 threads (8 waves x 32 Q-rows): same 2 blocks/CU (LDS-limited) but
//     16 waves/CU = 4/SIMD (was 2/SIMD) -> 2x latency hiding. Per-wave
//     accumulators halve, so __launch_bounds__(512,4) (<=128 VGPR) fits.
//   * Vt double-buffered -> ONE barrier per KV-iteration (was 2): Vt(t+1)
//     goes to the other buffer, so the "all waves done reading Vt" barrier
//     is gone. LDS = 36864(Q/P union) + 16384(Ks dbuf) + 18432(Vt dbuf)
//     = 71680 B -> still 2 blocks/CU.
//   * Ks XOR-swizzle via pre-swizzled GLOBAL source (DMA dest stays linear,
//     both-sides-or-neither rule): element (key, 16B-chunk q) lives at
//     linear chunk q ^ ((key>>1)&3); ds_read applies the same XOR. Spreads
//     each quarter-wave's ds_read_b128 over all 8 bank groups (was 2) ->
//     kills the dominant bank-conflict source.
// P/Vt share the colp(key) = (key&15)*4 + (key>>4) column permutation
// (contraction over k is permutation-invariant since P and V^T use the same
// key order).
// ---------------------------------------------------------------------------
__global__ __launch_bounds__(512, 4) void attn_mfma(const ushortT* __restrict__ Q,
                                                    const ushortT* __restrict__ K,
                                                    const ushortT* __restrict__ V,
                                                    ushortT* __restrict__ O) {
  __shared__ ushortT smemA[256 * 72];   // 36864 B (Qs staging uses first 32768)
  __shared__ ushortT Ks[2][64 * 64];    // 2 x 8192 B: [buf][c][key][32], swizzled chunks
  __shared__ ushortT Vt[2][64 * 72];    // 2 x 9216 B: [buf][dh][colp]

  const int tid = threadIdx.x;
  const int wave = tid >> 6, lane = tid & 63;
  const int quad = lane >> 4, lrow = lane & 15;
  const int bh = blockIdx.y;
  const int q0 = blockIdx.x * 256;

  const ushortT* qg = Q + (size_t)bh * Nc * DHc;
  const ushortT* kg = K + (size_t)bh * Nc * DHc;
  const ushortT* vg = V + (size_t)bh * Nc * DHc;

  // K staging swizzle: linear chunk slot (lane&3) receives global chunk
  // (lane&3) ^ f(key), f(key) = (key>>1)&3.  key = kb + (lane>>2), kb%16==0
  // -> f = (lane>>3)&3 (lane-only).
  const int ksw = (lane & 3) ^ ((lane >> 3) & 3);  // DMA source chunk
  const int krd = (lrow >> 1) & 3;                 // read-side XOR (key=nt*16+lrow)

  // K DMA shape: 512 threads stage one 64x64 bf16 tile (8 KB) in 1 load each.
  const int kc = wave & 1, kb = (wave >> 1) * 16;
  const int krow = kb + (lane >> 2);

  // Vt staging map: thread handles keys {kq+32*kh, kq+16+32*kh} x 4 dh.
  const int kq = tid & 15;
  const int dhg = ((tid >> 4) & 15) * 4;
  const int kh = tid >> 8;  // 0 or 1

  // ---- prologue: stage Q (256 rows), Ks[0]<-tile0, vreg<-V tile0 ----
#pragma unroll
  for (int c = 0; c < 2; ++c)
#pragma unroll
    for (int rh = 0; rh < 2; ++rh) {
      const int row = wave * 32 + rh * 16;
      GLD_LDS16(qg + (size_t)(q0 + row + (lane >> 2)) * DHc + c * 32 + (lane & 3) * 8,
                smemA + (c * 256 + row) * 32 + lane * 8);
    }
  GLD_LDS16(kg + (size_t)krow * DHc + kc * 32 + ksw * 8,
            &Ks[0][(kc * 64 + kb) * 32 + lane * 8]);
  u16x4 vreg[2];
#pragma unroll
  for (int j = 0; j < 2; ++j)
    vreg[j] = *(const u16x4*)(vg + (size_t)(kq + 16 * j + 32 * kh) * DHc + dhg);

  __syncthreads();  // Q + Ks0 staged (drains vmcnt, incl. vreg loads)

  // Q fragments -> registers (A-operand: m=lrow, k=quad*8+j)
  bf16x8 af_q[2][2];
#pragma unroll
  for (int mt = 0; mt < 2; ++mt)
#pragma unroll
    for (int ks = 0; ks < 2; ++ks)
      af_q[mt][ks] = *(const bf16x8*)(smemA +
          ((ks * 256 + wave * 32 + mt * 16 + lrow) * 32 + quad * 8));

  // Vt[0] <- tile0 (transpose+permute from regs)
#pragma unroll
  for (int d = 0; d < 4; ++d) {
    u16x2 t;
    t[0] = vreg[0][d];
    t[1] = vreg[1][d];
    *(u16x2*)(&Vt[0][(dhg + d) * 72 + kq * 4 + kh * 2]) = t;
  }
  __syncthreads();  // af_q reads done before Ps overwrites Qs; Vt0 visible

  f32x4 o_acc[2][4];
#pragma unroll
  for (int mt = 0; mt < 2; ++mt)
#pragma unroll
    for (int nt = 0; nt < 4; ++nt) o_acc[mt][nt] = (f32x4){0.f, 0.f, 0.f, 0.f};
  float l_i[8];
#pragma unroll
  for (int i = 0; i < 8; ++i) l_i[i] = 0.f;

  for (int k0 = 0; k0 < Nc; k0 += 64) {
    const int cur = (k0 >> 6) & 1, nxt = cur ^ 1;
    const bool pref = (k0 + 64 < Nc);

    // ---- top-of-iter prefetch for tile t+1 (overlaps this whole iter) ----
    if (pref) {
      GLD_LDS16(kg + (size_t)(k0 + 64 + krow) * DHc + kc * 32 + ksw * 8,
                &Ks[nxt][(kc * 64 + kb) * 32 + lane * 8]);
#pragma unroll
      for (int j = 0; j < 2; ++j)
        vreg[j] = *(const u16x4*)(vg + (size_t)(k0 + 64 + kq + 16 * j + 32 * kh) * DHc + dhg);
    }

    // ---- S = Q @ K^T (scale pre-folded into Q) ----
    bf16x8 bf_k[4][2];
#pragma unroll
    for (int nt = 0; nt < 4; ++nt)
#pragma unroll
      for (int ks = 0; ks < 2; ++ks)
        bf_k[nt][ks] = *(const bf16x8*)(
            &Ks[cur][(ks * 64 + nt * 16 + lrow) * 32 + (quad ^ krd) * 8]);

    f32x4 s_acc[2][4];
#pragma unroll
    for (int mt = 0; mt < 2; ++mt)
#pragma unroll
      for (int nt = 0; nt < 4; ++nt) {
        s_acc[mt][nt] = (f32x4){0.f, 0.f, 0.f, 0.f};
#pragma unroll
        for (int ks = 0; ks < 2; ++ks)
          s_acc[mt][nt] = __builtin_amdgcn_mfma_f32_16x16x32_bf16(
              af_q[mt][ks], bf_k[nt][ks], s_acc[mt][nt], 0, 0, 0);
      }

    // ---- P = exp2(S); partial row-sums; P -> LDS (bf16, colp layout) ----
#pragma unroll
    for (int mt = 0; mt < 2; ++mt) {
#pragma unroll
      for (int r = 0; r < 4; ++r) {
        const float p0 = fexp2(s_acc[mt][0][r]);
        const float p1 = fexp2(s_acc[mt][1][r]);
        const float p2 = fexp2(s_acc[mt][2][r]);
        const float p3 = fexp2(s_acc[mt][3][r]);
        l_i[mt * 4 + r] += (p0 + p1) + (p2 + p3);
        const unsigned pk01 = __builtin_amdgcn_perm(
            __float_as_uint(p1), __float_as_uint(p0), 0x07060302u);
        const unsigned pk23 = __builtin_amdgcn_perm(
            __float_as_uint(p3), __float_as_uint(p2), 0x07060302u);
        const int row = wave * 32 + mt * 16 + quad * 4 + r;
        *(uint2*)(smemA + row * 72 + lrow * 4) = make_uint2(pk01, pk23);
      }
    }
    // P is wave-local: drain LDS writes, no barrier.
    asm volatile("s_waitcnt lgkmcnt(0)" ::: "memory");

    // ---- O += P @ V  (reads Vt[cur]) ----
    bf16x8 af_p[2][2], bf_v[4][2];
#pragma unroll
    for (int mt = 0; mt < 2; ++mt)
#pragma unroll
      for (int ks = 0; ks < 2; ++ks)
        af_p[mt][ks] = *(const bf16x8*)(smemA +
            (wave * 32 + mt * 16 + lrow) * 72 + ks * 32 + quad * 8);
#pragma unroll
    for (int nt = 0; nt < 4; ++nt)
#pragma unroll
      for (int ks = 0; ks < 2; ++ks)
        bf_v[nt][ks] = *(const bf16x8*)(
            &Vt[cur][(nt * 16 + lrow) * 72 + ks * 32 + quad * 8]);
#pragma unroll
    for (int mt = 0; mt < 2; ++mt)
#pragma unroll
      for (int nt = 0; nt < 4; ++nt)
#pragma unroll
        for (int ks = 0; ks < 2; ++ks)
          o_acc[mt][nt] = __builtin_amdgcn_mfma_f32_16x16x32_bf16(
              af_p[mt][ks], bf_v[nt][ks], o_acc[mt][nt], 0, 0, 0);

    // ---- Vt[nxt] <- tile t+1 from prefetched regs (vmcnt wait auto) ----
    if (pref) {
#pragma unroll
      for (int d = 0; d < 4; ++d) {
        u16x2 t;
        t[0] = vreg[0][d];
        t[1] = vreg[1][d];
        *(u16x2*)(&Vt[nxt][(dhg + d) * 72 + kq * 4 + kh * 2]) = t;
      }
    }

    // single loop barrier: Vt[nxt] + Ks[nxt] (DMA issued at top) drained by
    // the implicit vmcnt(0)+lgkmcnt(0) here; Vt[cur]/Ks[cur]/P reads of this
    // iter all precede it, so next iter's overwrites are safe.
    __syncthreads();
  }

  // ---- final l reduction across the 16 lrow lanes ----
#pragma unroll
  for (int i = 0; i < 8; ++i) {
    float s = l_i[i];
#pragma unroll
    for (int off = 8; off >= 1; off >>= 1) s += __shfl_xor(s, off, 16);
    l_i[i] = s;
  }

  // ---- epilogue: O[b, n, h*64+dh] = o_acc / l ----
  const int b = bh / Hc, h = bh % Hc;
#pragma unroll
  for (int mt = 0; mt < 2; ++mt) {
#pragma unroll
    for (int r = 0; r < 4; ++r) {
      const float inv_l = 1.0f / l_i[mt * 4 + r];
      const int n = q0 + wave * 32 + mt * 16 + quad * 4 + r;
      const size_t base = ((size_t)b * Nc + n) * Dc + h * DHc;
#pragma unroll
      for (int nt = 0; nt < 4; ++nt)
        O[base + nt * 16 + lrow] = f2bf(o_acc[mt][nt][r] * inv_l);
    }
  }
}

// ---------------------------------------------------------------------------
extern "C" void kernel_launch(void* const* d_in, const int* in_sizes, int n_in,
                              void* d_out, int out_size, void* d_ws,
                              size_t ws_size, hipStream_t stream) {
  const float* x  = (const float*)d_in[0];
  const float* Wq = (const float*)d_in[2];
  const float* Wk = (const float*)d_in[3];
  const float* Wv = (const float*)d_in[4];
  const float* Wo = (const float*)d_in[5];

  ushortT* ws16 = (ushortT*)d_ws;
  ushortT* xb   = ws16;
  ushortT* wqb  = xb + (size_t)Mrows * Dc;
  ushortT* qkvb = wqb + 4 * (size_t)Dc * Dc;
  ushortT* qb   = qkvb;
  ushortT* kb   = qb + (size_t)Mrows * Dc;
  ushortT* vb   = kb + (size_t)Mrows * Dc;
  ushortT* aob  = vb + (size_t)Mrows * Dc;
  ushortT* wob  = wqb + 3 * (size_t)Dc * Dc;

  dim3 blk(256);
  hipLaunchKernelGGL(cvt_kernel, dim3(12288), blk, 0, stream, x, Wq, Wk, Wv, Wo,
                     ws16);

  hipLaunchKernelGGL((mfma_gemm<1>), dim3(24, Mrows / 128), blk, 0, stream, xb,
                     wqb, (void*)qkvb);

  hipLaunchKernelGGL(attn_mfma, dim3(Nc / 256, Bc * Hc), dim3(512), 0, stream,
                     qb, kb, vb, aob);

  hipLaunchKernelGGL((mfma_gemm<0>), dim3(8, Mrows / 128), blk, 0, stream, aob,
                     wob, d_out);
}

// Round 3
// 292.805 us; speedup vs baseline: 1.1447x; 1.1447x over previous
//
#include <hip/hip_runtime.h>
#include <math.h>

// Problem constants: B=4, N=2048, D=1024, H=16, DH=64
constexpr int Bc  = 4;
constexpr int Nc  = 2048;
constexpr int Dc  = 1024;
constexpr int Hc  = 16;
constexpr int DHc = 64;
constexpr int Mrows = Bc * Nc;  // 8192

typedef unsigned short ushortT;
typedef __attribute__((ext_vector_type(8))) short bf16x8;
typedef __attribute__((ext_vector_type(2))) unsigned short u16x2;
typedef __attribute__((ext_vector_type(4))) unsigned short u16x4;
typedef __attribute__((ext_vector_type(4))) float f32x4;

// 1/sqrt(DH) * log2(e): folded into Q so softmax is exp2(s) directly.
#define QSCALE 0.18033688011112043f

// async global->LDS, 16B per lane; LDS dest must be wave-uniform base + lane*16
#define GLD_LDS16(g, l)                                                        \
  __builtin_amdgcn_global_load_lds(                                            \
      (const __attribute__((address_space(1))) void*)(g),                      \
      (__attribute__((address_space(3))) void*)(l), 16, 0, 0)

__device__ inline ushortT f2bf(float f) {
  unsigned int u = __float_as_uint(f);
  u += 0x7fffu + ((u >> 16) & 1u);  // round-to-nearest-even
  return (ushortT)(u >> 16);
}

// fast 2^x on the transcendental pipe (v_exp_f32)
__device__ inline float fexp2(float x) { return __builtin_amdgcn_exp2f(x); }

// ---------------------------------------------------------------------------
// fp32 -> bf16 conversion of x and the 4 weight matrices (unchanged, verified)
// ---------------------------------------------------------------------------
__global__ __launch_bounds__(256) void cvt_kernel(
    const float* __restrict__ x, const float* __restrict__ wq,
    const float* __restrict__ wk, const float* __restrict__ wv,
    const float* __restrict__ wo, ushortT* __restrict__ dst) {
  const int g = blockIdx.x * 256 + threadIdx.x;  // float4 index
  const float* src;
  size_t soff, doff;
  if (g < 2097152) {
    src = x;
    soff = (size_t)g * 4;
    doff = soff;
  } else {
    const int t = g - 2097152;
    const int w = t >> 18;
    const int off = t & 262143;
    src = (w == 0) ? wq : (w == 1) ? wk : (w == 2) ? wv : wo;
    soff = (size_t)off * 4;
    doff = 8388608u + (size_t)w * 1048576u + (size_t)off * 4;
  }
  float4 v = *(const float4*)(src + soff);
  ushort4 o = make_ushort4(f2bf(v.x), f2bf(v.y), f2bf(v.z), f2bf(v.w));
  *(ushort4*)(dst + doff) = o;
}

// ---------------------------------------------------------------------------
// MFMA GEMM C = A @ W^T.  BK=64 via two m97-layout 32-k panels: 32 MFMA per
// barrier pair (halves barrier-drain count vs BK=32). LDS 32 KB.
// QKV=1: wsel=bx>>3 selects Wq/Wk/Wv; Q output (wsel==0) pre-scaled by QSCALE.
// (unchanged this round)
// ---------------------------------------------------------------------------
template <int QKV>
__global__ __launch_bounds__(256) void mfma_gemm(const ushortT* __restrict__ A,
                                                 const ushortT* __restrict__ W0,
                                                 void* __restrict__ C0) {
  __shared__ ushortT As[2][128 * 32];  // [panel][row][32]
  __shared__ ushortT Bs[2][128 * 32];

  const int tid = threadIdx.x;
  const int wave = tid >> 6, lane = tid & 63;
  const int quad = lane >> 4, lrow = lane & 15;
  const int bx = blockIdx.x, by = blockIdx.y;
  const int wsel = QKV ? (bx >> 3) : 0;
  const int e0 = QKV ? ((bx & 7) * 128) : (bx * 128);
  const int m0 = by * 128;
  const ushortT* Wp = W0 + (size_t)wsel * (Dc * Dc);
  const float oscale = (QKV && wsel == 0) ? QSCALE : 1.0f;

  const ushortT* ag = A  + (size_t)(m0 + wave * 32 + (lane >> 2)) * Dc + (lane & 3) * 8;
  const ushortT* bg = Wp + (size_t)(e0 + wave * 32 + (lane >> 2)) * Dc + (lane & 3) * 8;
  const int lbase = wave * 1024 + lane * 8;

  f32x4 acc[4][4];
#pragma unroll
  for (int i = 0; i < 4; ++i)
#pragma unroll
    for (int j = 0; j < 4; ++j) acc[i][j] = (f32x4){0.f, 0.f, 0.f, 0.f};

  const int wm = (wave >> 1) * 64, wn = (wave & 1) * 64;

  for (int k0 = 0; k0 < Dc; k0 += 64) {
    __syncthreads();
#pragma unroll
    for (int p = 0; p < 2; ++p) {
      GLD_LDS16(ag + p * 32, &As[p][lbase]);
      GLD_LDS16(ag + p * 32 + 16 * Dc, &As[p][lbase + 512]);
      GLD_LDS16(bg + p * 32, &Bs[p][lbase]);
      GLD_LDS16(bg + p * 32 + 16 * Dc, &Bs[p][lbase + 512]);
    }
    ag += 64;
    bg += 64;
    __syncthreads();

#pragma unroll
    for (int p = 0; p < 2; ++p) {
      bf16x8 af[4], bf[4];
#pragma unroll
      for (int mt = 0; mt < 4; ++mt)
        af[mt] = *(const bf16x8*)(&As[p][(wm + mt * 16 + lrow) * 32 + quad * 8]);
#pragma unroll
      for (int nt = 0; nt < 4; ++nt)
        bf[nt] = *(const bf16x8*)(&Bs[p][(wn + nt * 16 + lrow) * 32 + quad * 8]);
#pragma unroll
      for (int mt = 0; mt < 4; ++mt)
#pragma unroll
        for (int nt = 0; nt < 4; ++nt)
          acc[mt][nt] = __builtin_amdgcn_mfma_f32_16x16x32_bf16(
              af[mt], bf[nt], acc[mt][nt], 0, 0, 0);
    }
  }

#pragma unroll
  for (int mt = 0; mt < 4; ++mt) {
#pragma unroll
    for (int nt = 0; nt < 4; ++nt) {
#pragma unroll
      for (int r = 0; r < 4; ++r) {
        const int m = m0 + wm + mt * 16 + quad * 4 + r;
        const int e = e0 + wn + nt * 16 + lrow;
        const float v = acc[mt][nt][r] * oscale;
        if (QKV) {
          const int b = m >> 11, n = m & 2047;
          const int h = e >> 6, dh = e & 63;
          ushortT* C = (ushortT*)C0 + (size_t)wsel * ((size_t)Mrows * Dc);
          C[(((size_t)(b * Hc + h)) * Nc + n) * DHc + dh] = f2bf(v);
        } else {
          ((float*)C0)[(size_t)m * Dc + e] = v;
        }
      }
    }
  }
}

// ---------------------------------------------------------------------------
// MFMA flash attention, fixed-m softmax. BQ=256, 512 threads (8 waves x 32
// Q-rows), Vt double-buffered -> ONE barrier per KV-iteration, Ks staged via
// pre-swizzled global source.
//
// Round-7 fix: round 6's __launch_bounds__(512, 4) capped the allocator at 64
// arch-VGPRs -> massive scratch spill (WRITE_SIZE 16 MB -> 320 MB, attn 106
// -> 168 us). (512, 2) relaxes the cap; natural usage is ~100-125 VGPR (acc
// arrays live in AGPRs on the gfx950 unified file), which still permits
// 2 blocks/CU = 16 waves/CU = 4 waves/SIMD -- the intended occupancy doubling
// without spill. LDS = 71680 B (2 blocks/CU).
// ---------------------------------------------------------------------------
__global__ __launch_bounds__(512, 2) void attn_mfma(const ushortT* __restrict__ Q,
                                                    const ushortT* __restrict__ K,
                                                    const ushortT* __restrict__ V,
                                                    ushortT* __restrict__ O) {
  __shared__ ushortT smemA[256 * 72];   // 36864 B (Qs staging uses first 32768)
  __shared__ ushortT Ks[2][64 * 64];    // 2 x 8192 B: [buf][c][key][32], swizzled chunks
  __shared__ ushortT Vt[2][64 * 72];    // 2 x 9216 B: [buf][dh][colp]

  const int tid = threadIdx.x;
  const int wave = tid >> 6, lane = tid & 63;
  const int quad = lane >> 4, lrow = lane & 15;
  const int bh = blockIdx.y;
  const int q0 = blockIdx.x * 256;

  const ushortT* qg = Q + (size_t)bh * Nc * DHc;
  const ushortT* kg = K + (size_t)bh * Nc * DHc;
  const ushortT* vg = V + (size_t)bh * Nc * DHc;

  // K staging swizzle: linear chunk slot (lane&3) receives global chunk
  // (lane&3) ^ f(key), f(key) = (key>>1)&3.  key = kb + (lane>>2), kb%16==0
  // -> f = (lane>>3)&3 (lane-only).
  const int ksw = (lane & 3) ^ ((lane >> 3) & 3);  // DMA source chunk
  const int krd = (lrow >> 1) & 3;                 // read-side XOR (key=nt*16+lrow)

  // K DMA shape: 512 threads stage one 64x64 bf16 tile (8 KB) in 1 load each.
  const int kc = wave & 1, kb = (wave >> 1) * 16;
  const int krow = kb + (lane >> 2);

  // Vt staging map: thread handles keys {kq+32*kh, kq+16+32*kh} x 4 dh.
  const int kq = tid & 15;
  const int dhg = ((tid >> 4) & 15) * 4;
  const int kh = tid >> 8;  // 0 or 1

  // ---- prologue: stage Q (256 rows), Ks[0]<-tile0, vreg<-V tile0 ----
#pragma unroll
  for (int c = 0; c < 2; ++c)
#pragma unroll
    for (int rh = 0; rh < 2; ++rh) {
      const int row = wave * 32 + rh * 16;
      GLD_LDS16(qg + (size_t)(q0 + row + (lane >> 2)) * DHc + c * 32 + (lane & 3) * 8,
                smemA + (c * 256 + row) * 32 + lane * 8);
    }
  GLD_LDS16(kg + (size_t)krow * DHc + kc * 32 + ksw * 8,
            &Ks[0][(kc * 64 + kb) * 32 + lane * 8]);
  u16x4 vreg[2];
#pragma unroll
  for (int j = 0; j < 2; ++j)
    vreg[j] = *(const u16x4*)(vg + (size_t)(kq + 16 * j + 32 * kh) * DHc + dhg);

  __syncthreads();  // Q + Ks0 staged (drains vmcnt, incl. vreg loads)

  // Q fragments -> registers (A-operand: m=lrow, k=quad*8+j)
  bf16x8 af_q[2][2];
#pragma unroll
  for (int mt = 0; mt < 2; ++mt)
#pragma unroll
    for (int ks = 0; ks < 2; ++ks)
      af_q[mt][ks] = *(const bf16x8*)(smemA +
          ((ks * 256 + wave * 32 + mt * 16 + lrow) * 32 + quad * 8));

  // Vt[0] <- tile0 (transpose+permute from regs)
#pragma unroll
  for (int d = 0; d < 4; ++d) {
    u16x2 t;
    t[0] = vreg[0][d];
    t[1] = vreg[1][d];
    *(u16x2*)(&Vt[0][(dhg + d) * 72 + kq * 4 + kh * 2]) = t;
  }
  __syncthreads();  // af_q reads done before Ps overwrites Qs; Vt0 visible

  f32x4 o_acc[2][4];
#pragma unroll
  for (int mt = 0; mt < 2; ++mt)
#pragma unroll
    for (int nt = 0; nt < 4; ++nt) o_acc[mt][nt] = (f32x4){0.f, 0.f, 0.f, 0.f};
  float l_i[8];
#pragma unroll
  for (int i = 0; i < 8; ++i) l_i[i] = 0.f;

  for (int k0 = 0; k0 < Nc; k0 += 64) {
    const int cur = (k0 >> 6) & 1, nxt = cur ^ 1;
    const bool pref = (k0 + 64 < Nc);

    // ---- top-of-iter prefetch for tile t+1 (overlaps this whole iter) ----
    if (pref) {
      GLD_LDS16(kg + (size_t)(k0 + 64 + krow) * DHc + kc * 32 + ksw * 8,
                &Ks[nxt][(kc * 64 + kb) * 32 + lane * 8]);
#pragma unroll
      for (int j = 0; j < 2; ++j)
        vreg[j] = *(const u16x4*)(vg + (size_t)(k0 + 64 + kq + 16 * j + 32 * kh) * DHc + dhg);
    }

    // ---- S = Q @ K^T (scale pre-folded into Q) ----
    bf16x8 bf_k[4][2];
#pragma unroll
    for (int nt = 0; nt < 4; ++nt)
#pragma unroll
      for (int ks = 0; ks < 2; ++ks)
        bf_k[nt][ks] = *(const bf16x8*)(
            &Ks[cur][(ks * 64 + nt * 16 + lrow) * 32 + (quad ^ krd) * 8]);

    f32x4 s_acc[2][4];
#pragma unroll
    for (int mt = 0; mt < 2; ++mt)
#pragma unroll
      for (int nt = 0; nt < 4; ++nt) {
        s_acc[mt][nt] = (f32x4){0.f, 0.f, 0.f, 0.f};
#pragma unroll
        for (int ks = 0; ks < 2; ++ks)
          s_acc[mt][nt] = __builtin_amdgcn_mfma_f32_16x16x32_bf16(
              af_q[mt][ks], bf_k[nt][ks], s_acc[mt][nt], 0, 0, 0);
      }

    // ---- P = exp2(S); partial row-sums; P -> LDS (bf16, colp layout) ----
#pragma unroll
    for (int mt = 0; mt < 2; ++mt) {
#pragma unroll
      for (int r = 0; r < 4; ++r) {
        const float p0 = fexp2(s_acc[mt][0][r]);
        const float p1 = fexp2(s_acc[mt][1][r]);
        const float p2 = fexp2(s_acc[mt][2][r]);
        const float p3 = fexp2(s_acc[mt][3][r]);
        l_i[mt * 4 + r] += (p0 + p1) + (p2 + p3);
        const unsigned pk01 = __builtin_amdgcn_perm(
            __float_as_uint(p1), __float_as_uint(p0), 0x07060302u);
        const unsigned pk23 = __builtin_amdgcn_perm(
            __float_as_uint(p3), __float_as_uint(p2), 0x07060302u);
        const int row = wave * 32 + mt * 16 + quad * 4 + r;
        *(uint2*)(smemA + row * 72 + lrow * 4) = make_uint2(pk01, pk23);
      }
    }
    // P is wave-local: drain LDS writes, no barrier.
    asm volatile("s_waitcnt lgkmcnt(0)" ::: "memory");

    // ---- O += P @ V  (reads Vt[cur]) ----
    bf16x8 af_p[2][2], bf_v[4][2];
#pragma unroll
    for (int mt = 0; mt < 2; ++mt)
#pragma unroll
      for (int ks = 0; ks < 2; ++ks)
        af_p[mt][ks] = *(const bf16x8*)(smemA +
            (wave * 32 + mt * 16 + lrow) * 72 + ks * 32 + quad * 8);
#pragma unroll
    for (int nt = 0; nt < 4; ++nt)
#pragma unroll
      for (int ks = 0; ks < 2; ++ks)
        bf_v[nt][ks] = *(const bf16x8*)(
            &Vt[cur][(nt * 16 + lrow) * 72 + ks * 32 + quad * 8]);
#pragma unroll
    for (int mt = 0; mt < 2; ++mt)
#pragma unroll
      for (int nt = 0; nt < 4; ++nt)
#pragma unroll
        for (int ks = 0; ks < 2; ++ks)
          o_acc[mt][nt] = __builtin_amdgcn_mfma_f32_16x16x32_bf16(
              af_p[mt][ks], bf_v[nt][ks], o_acc[mt][nt], 0, 0, 0);

    // ---- Vt[nxt] <- tile t+1 from prefetched regs (vmcnt wait auto) ----
    if (pref) {
#pragma unroll
      for (int d = 0; d < 4; ++d) {
        u16x2 t;
        t[0] = vreg[0][d];
        t[1] = vreg[1][d];
        *(u16x2*)(&Vt[nxt][(dhg + d) * 72 + kq * 4 + kh * 2]) = t;
      }
    }

    // single loop barrier: Vt[nxt] + Ks[nxt] (DMA issued at top) drained by
    // the implicit vmcnt(0)+lgkmcnt(0) here; Vt[cur]/Ks[cur]/P reads of this
    // iter all precede it, so next iter's overwrites are safe.
    __syncthreads();
  }

  // ---- final l reduction across the 16 lrow lanes ----
#pragma unroll
  for (int i = 0; i < 8; ++i) {
    float s = l_i[i];
#pragma unroll
    for (int off = 8; off >= 1; off >>= 1) s += __shfl_xor(s, off, 16);
    l_i[i] = s;
  }

  // ---- epilogue: O[b, n, h*64+dh] = o_acc / l ----
  const int b = bh / Hc, h = bh % Hc;
#pragma unroll
  for (int mt = 0; mt < 2; ++mt) {
#pragma unroll
    for (int r = 0; r < 4; ++r) {
      const float inv_l = 1.0f / l_i[mt * 4 + r];
      const int n = q0 + wave * 32 + mt * 16 + quad * 4 + r;
      const size_t base = ((size_t)b * Nc + n) * Dc + h * DHc;
#pragma unroll
      for (int nt = 0; nt < 4; ++nt)
        O[base + nt * 16 + lrow] = f2bf(o_acc[mt][nt][r] * inv_l);
    }
  }
}

// ---------------------------------------------------------------------------
extern "C" void kernel_launch(void* const* d_in, const int* in_sizes, int n_in,
                              void* d_out, int out_size, void* d_ws,
                              size_t ws_size, hipStream_t stream) {
  const float* x  = (const float*)d_in[0];
  const float* Wq = (const float*)d_in[2];
  const float* Wk = (const float*)d_in[3];
  const float* Wv = (const float*)d_in[4];
  const float* Wo = (const float*)d_in[5];

  ushortT* ws16 = (ushortT*)d_ws;
  ushortT* xb   = ws16;
  ushortT* wqb  = xb + (size_t)Mrows * Dc;
  ushortT* qkvb = wqb + 4 * (size_t)Dc * Dc;
  ushortT* qb   = qkvb;
  ushortT* kb   = qb + (size_t)Mrows * Dc;
  ushortT* vb   = kb + (size_t)Mrows * Dc;
  ushortT* aob  = vb + (size_t)Mrows * Dc;
  ushortT* wob  = wqb + 3 * (size_t)Dc * Dc;

  dim3 blk(256);
  hipLaunchKernelGGL(cvt_kernel, dim3(12288), blk, 0, stream, x, Wq, Wk, Wv, Wo,
                     ws16);

  hipLaunchKernelGGL((mfma_gemm<1>), dim3(24, Mrows / 128), blk, 0, stream, xb,
                     wqb, (void*)qkvb);

  hipLaunchKernelGGL(attn_mfma, dim3(Nc / 256, Bc * Hc), dim3(512), 0, stream,
                     qb, kb, vb, aob);

  hipLaunchKernelGGL((mfma_gemm<0>), dim3(8, Mrows / 128), blk, 0, stream, aob,
                     wob, d_out);
}